// Round 1
// baseline (393.823 us; speedup 1.0000x reference)
//
#include <hip/hip_runtime.h>

#define N_NODES_C 500000
#define NODE_DIM_C 128
#define HIDDEN_C 64
#define N_GRAPHS_C 16384

// Prep: transpose W1 [64][128] -> W1T [128][64] into ws; zero the totals
// region of d_out (harness re-poisons d_out to 0xAA before every launch).
__global__ void prep_kernel(const float* __restrict__ W1,
                            float* __restrict__ W1T,
                            float* __restrict__ total) {
    int i = blockIdx.x * 256 + threadIdx.x;
    if (i < N_GRAPHS_C) total[i] = 0.0f;
    if (i < NODE_DIM_C * HIDDEN_C) {
        int k = i >> 6;   // / HIDDEN_C
        int h = i & 63;   // % HIDDEN_C
        W1T[i] = W1[h * NODE_DIM_C + k];
    }
}

// Fused: per-node MLP (128->64, SiLU, 64->1) + residual + sorted-segment sum.
// thread = node; 64 f32 accumulators; weights come in through the scalar pipe
// (uniform-indexed __restrict__ loads -> s_load), x row streamed as float4.
__global__ __launch_bounds__(256, 4) void energy_kernel(
    const float* __restrict__ x,
    const float* __restrict__ ae_in,
    const int* __restrict__ batch,
    const float* __restrict__ W1T,
    const float* __restrict__ b1,
    const float* __restrict__ W2,
    const float* __restrict__ b2,
    float* __restrict__ out_ae,
    float* __restrict__ out_total)
{
    const int n = blockIdx.x * 256 + threadIdx.x;
    const bool active = (n < N_NODES_C);
    const int nc = active ? n : (N_NODES_C - 1);

    float acc[HIDDEN_C];
    {
        const float4* b14 = reinterpret_cast<const float4*>(b1);
#pragma unroll
        for (int j = 0; j < HIDDEN_C / 4; ++j) {
            float4 b = b14[j];
            acc[4 * j + 0] = b.x; acc[4 * j + 1] = b.y;
            acc[4 * j + 2] = b.z; acc[4 * j + 3] = b.w;
        }
    }

    const float4* xr = reinterpret_cast<const float4*>(x + (size_t)nc * NODE_DIM_C);

    // 2-stage prefetch of the node row, 16 floats (64 B) per stage.
    float4 c0 = xr[0], c1 = xr[1], c2 = xr[2], c3 = xr[3];

#pragma unroll 1
    for (int kc = 0; kc < NODE_DIM_C; kc += 16) {
        const int nk = ((kc + 16) & (NODE_DIM_C - 1)) >> 2;  // wraps on last iter (cheap L1 hit)
        float4 n0 = xr[nk + 0], n1 = xr[nk + 1], n2 = xr[nk + 2], n3 = xr[nk + 3];

        const float xk[16] = {c0.x, c0.y, c0.z, c0.w, c1.x, c1.y, c1.z, c1.w,
                              c2.x, c2.y, c2.z, c2.w, c3.x, c3.y, c3.z, c3.w};
#pragma unroll
        for (int kk = 0; kk < 16; ++kk) {
            // wave-uniform index -> scalar loads (s_load_dwordx4), weight rides
            // the single SGPR operand of v_fma_f32.
            const float4* w4 = reinterpret_cast<const float4*>(W1T + (kc + kk) * HIDDEN_C);
            const float xv = xk[kk];
#pragma unroll
            for (int j = 0; j < HIDDEN_C / 4; ++j) {
                float4 w = w4[j];
                acc[4 * j + 0] = fmaf(xv, w.x, acc[4 * j + 0]);
                acc[4 * j + 1] = fmaf(xv, w.y, acc[4 * j + 1]);
                acc[4 * j + 2] = fmaf(xv, w.z, acc[4 * j + 2]);
                acc[4 * j + 3] = fmaf(xv, w.w, acc[4 * j + 3]);
            }
        }
        c0 = n0; c1 = n1; c2 = n2; c3 = n3;
    }

    // Epilogue: SiLU + dot with W2 + b2.
    float e = b2[0];
    {
        const float4* w24 = reinterpret_cast<const float4*>(W2);
#pragma unroll
        for (int j = 0; j < HIDDEN_C / 4; ++j) {
            float4 w = w24[j];
#pragma unroll
            for (int q = 0; q < 4; ++q) {
                float v = acc[4 * j + q];
                float wq = (q == 0) ? w.x : (q == 1) ? w.y : (q == 2) ? w.z : w.w;
                float ex = __expf(-v);                       // v_exp_f32 path
                float sig = __builtin_amdgcn_rcpf(1.0f + ex); // v_rcp_f32
                e = fmaf(wq * v, sig, e);                     // w * silu(v)
            }
        }
    }

    float ae = ae_in[nc] + e;
    if (active) out_ae[n] = ae;

    // Sorted-segment sum: wave-level segmented inclusive scan, then one
    // atomic per run boundary. Inactive lanes carry g=-1 / val=0 (no early
    // return so shuffles stay wave-converged).
    int g = active ? batch[n] : -1;
    float val = active ? ae : 0.0f;
    const int lane = threadIdx.x & 63;
#pragma unroll
    for (int off = 1; off < 64; off <<= 1) {
        float o = __shfl_up(val, off, 64);
        int og = __shfl_up(g, off, 64);
        if (lane >= off && og == g) val += o;
    }
    int gn = __shfl_down(g, 1, 64);
    bool lastlane = (lane == 63) || (gn != g);
    if (lastlane && g >= 0) atomicAdd(&out_total[g], val);
}

extern "C" void kernel_launch(void* const* d_in, const int* in_sizes, int n_in,
                              void* d_out, int out_size, void* d_ws, size_t ws_size,
                              hipStream_t stream) {
    const float* x     = (const float*)d_in[0];
    const float* ae    = (const float*)d_in[1];
    const int*   batch = (const int*)d_in[2];
    const float* W1    = (const float*)d_in[3];
    const float* b1    = (const float*)d_in[4];
    const float* W2    = (const float*)d_in[5];
    const float* b2    = (const float*)d_in[6];

    float* out_ae    = (float*)d_out;
    float* out_total = out_ae + N_NODES_C;
    float* W1T       = (float*)d_ws;   // 128*64*4 = 32 KB scratch

    prep_kernel<<<64, 256, 0, stream>>>(W1, W1T, out_total);

    const int blocks = (N_NODES_C + 255) / 256;
    energy_kernel<<<blocks, 256, 0, stream>>>(x, ae, batch, W1T, b1, W2, b2,
                                              out_ae, out_total);
}